// Round 4
// baseline (790.420 us; speedup 1.0000x reference)
//
#include <hip/hip_runtime.h>

typedef __attribute__((ext_vector_type(8))) short short8;
typedef __attribute__((ext_vector_type(4))) float f32x4;

#define NODE_D 128
#define SCAN_T 256
#define SCAN_I 8
#define BSH 7              // bucket = 128 consecutive dst nodes

__device__ __forceinline__ float bf2f(ushort u) {
    union { uint i; float f; } c; c.i = ((uint)u) << 16; return c.f;
}
__device__ __forceinline__ ushort f2bf(float f) {
    union { float f; uint i; } c; c.f = f;
    return (ushort)((c.i + 0x7FFF + ((c.i >> 16) & 1)) >> 16);
}

// ---------- all 7 weight matrices f32 -> bf16, concatenated dst ----------
__global__ __launch_bounds__(256) void k_cvt_w(const float* __restrict__ s0, const float* __restrict__ s1,
                                               const float* __restrict__ s2, const float* __restrict__ s3,
                                               const float* __restrict__ s4, const float* __restrict__ s5,
                                               const float* __restrict__ s6, ushort* __restrict__ dst) {
    int i = blockIdx.x * 256 + threadIdx.x;
    if (i >= 98304) return;
    const float* s; int off;
    if (i < 16384)      { s = s0; off = i; }
    else if (i < 32768) { s = s1; off = i - 16384; }
    else if (i < 49152) { s = s2; off = i - 32768; }
    else if (i < 65536) { s = s3; off = i - 49152; }
    else if (i < 81920) { s = s4; off = i - 65536; }
    else if (i < 90112) { s = s5; off = i - 81920; }
    else                { s = s6; off = i - 90112; }
    dst[i] = f2bf(s[off]);
}

// ---------- degree histogram ----------
__global__ __launch_bounds__(256) void k_hist(const int* __restrict__ dst,
                                              int* __restrict__ deg, int E) {
    int i = blockIdx.x * 256 + threadIdx.x;
    if (i < E) atomicAdd(&deg[dst[i]], 1);
}

// ---------- scan pass A ----------
__global__ __launch_bounds__(SCAN_T) void k_scan_bsum(const int* __restrict__ deg,
                                                      int* __restrict__ bsums, int n) {
    __shared__ int red[SCAN_T];
    int base = blockIdx.x * SCAN_T * SCAN_I + threadIdx.x * SCAN_I;
    int s = 0;
    #pragma unroll
    for (int i = 0; i < SCAN_I; ++i) {
        int idx = base + i;
        if (idx < n) s += deg[idx];
    }
    red[threadIdx.x] = s;
    __syncthreads();
    for (int st = SCAN_T / 2; st > 0; st >>= 1) {
        if (threadIdx.x < st) red[threadIdx.x] += red[threadIdx.x + st];
        __syncthreads();
    }
    if (threadIdx.x == 0) bsums[blockIdx.x] = red[0];
}

// ---------- scan pass B ----------
__global__ void k_scan_bsum_excl(int* __restrict__ bsums, int nb,
                                 int* __restrict__ rowptr_last) {
    if (blockIdx.x == 0 && threadIdx.x == 0) {
        int run = 0;
        for (int i = 0; i < nb; ++i) {
            int v = bsums[i];
            bsums[i] = run;
            run += v;
        }
        rowptr_last[0] = run;
    }
}

// ---------- scan pass C ----------
__global__ __launch_bounds__(SCAN_T) void k_scan_final(const int* __restrict__ deg,
                                                       const int* __restrict__ bsums,
                                                       int* __restrict__ rowptr,
                                                       int* __restrict__ cursor, int n) {
    __shared__ int ts[SCAN_T];
    int base = blockIdx.x * SCAN_T * SCAN_I + threadIdx.x * SCAN_I;
    int v[SCAN_I];
    int s = 0;
    #pragma unroll
    for (int i = 0; i < SCAN_I; ++i) {
        int idx = base + i;
        v[i] = (idx < n) ? deg[idx] : 0;
        s += v[i];
    }
    ts[threadIdx.x] = s;
    __syncthreads();
    for (int st = 1; st < SCAN_T; st <<= 1) {
        int add = (threadIdx.x >= st) ? ts[threadIdx.x - st] : 0;
        __syncthreads();
        ts[threadIdx.x] += add;
        __syncthreads();
    }
    int excl = (threadIdx.x == 0 ? 0 : ts[threadIdx.x - 1]) + bsums[blockIdx.x];
    #pragma unroll
    for (int i = 0; i < SCAN_I; ++i) {
        int idx = base + i;
        if (idx < n) { rowptr[idx] = excl; cursor[idx] = excl; }
        excl += v[i];
    }
}

// ---------- bucket cursors = rowptr at bucket starts ----------
__global__ __launch_bounds__(256) void k_bcur(const int* __restrict__ rowptr,
                                              int* __restrict__ bcur, int nbk, int N) {
    int b = blockIdx.x * 256 + threadIdx.x;
    if (b < nbk) bcur[b] = rowptr[min(b << BSH, N)];
}

// ---------- pass 1: scatter edges into bucket-contiguous ebuf ----------
__global__ __launch_bounds__(256) void k_scatter(const int* __restrict__ src,
                                                 const int* __restrict__ dst,
                                                 int* __restrict__ bcur,
                                                 uint2* __restrict__ ebuf, int E) {
    int i = blockIdx.x * 256 + threadIdx.x;
    if (i < E) {
        int d = dst[i];
        int pos = atomicAdd(&bcur[d >> BSH], 1);
        uint2 e; e.x = (uint)src[i]; e.y = (uint)d;
        ebuf[pos] = e;
    }
}

// ---------- pass 2: per-bucket local CSR fill (L2-resident windows) ----------
__global__ __launch_bounds__(256) void k_fill2(const uint2* __restrict__ ebuf,
                                               const int* __restrict__ rowptr,
                                               int* __restrict__ cursor,
                                               int* __restrict__ col, int N) {
    int b = blockIdx.x;
    int lo = rowptr[min(b << BSH, N)];
    int hi = rowptr[min((b + 1) << BSH, N)];
    for (int j = lo + (int)threadIdx.x; j < hi; j += 256) {
        uint2 e = ebuf[j];
        int pos = atomicAdd(&cursor[e.y], 1);
        col[pos] = (int)e.x;
    }
}

// ---------- mean aggregation over bf16 activations: one wave per node ----------
template<int D>
__global__ __launch_bounds__(256) void k_aggb(const ushort* __restrict__ h,
                                              const int* __restrict__ rowptr,
                                              const int* __restrict__ col,
                                              ushort* __restrict__ mean, int N) {
    int node = blockIdx.x * 4 + (threadIdx.x >> 6);
    if (node >= N) return;
    int lane = threadIdx.x & 63;
    int beg = rowptr[node];
    int end = rowptr[node + 1];
    float inv = 1.f / fmaxf((float)(end - beg), 1.f);
    if constexpr (D == 128) {
        const ushort* base = h + lane * 2;
        float ax = 0.f, ay = 0.f;
        int j = beg;
        for (; j + 7 < end; j += 8) {
            uint v[8];
            #pragma unroll
            for (int q = 0; q < 8; ++q)
                v[q] = *(const uint*)(base + (size_t)col[j + q] * 128);
            #pragma unroll
            for (int q = 0; q < 8; ++q) {
                ax += bf2f((ushort)v[q]);
                ay += bf2f((ushort)(v[q] >> 16));
            }
        }
        for (; j < end; ++j) {
            uint v = *(const uint*)(base + (size_t)col[j] * 128);
            ax += bf2f((ushort)v);
            ay += bf2f((ushort)(v >> 16));
        }
        uint o = (uint)f2bf(ax * inv) | ((uint)f2bf(ay * inv) << 16);
        *(uint*)(mean + (size_t)node * 128 + lane * 2) = o;
    } else {
        const ushort* base = h + lane;
        float ax = 0.f;
        int j = beg;
        for (; j + 7 < end; j += 8) {
            ushort v[8];
            #pragma unroll
            for (int q = 0; q < 8; ++q) v[q] = base[(size_t)col[j + q] * D];
            #pragma unroll
            for (int q = 0; q < 8; ++q) ax += bf2f(v[q]);
        }
        for (; j < end; ++j) ax += bf2f(base[(size_t)col[j] * D]);
        mean[(size_t)node * D + lane] = f2bf(ax * inv);
    }
}

// ---------- MFMA dense: out = A@W0^T (+ A1@W1^T) [+bias] [+add] [+relu] ----------
// A0: [N][128] bf16 (or f32 if A0F32) row-major. W: [OD][128] bf16 row-major.
// Tile: 128 rows x OD cols, 4 waves. LDS [dim][64] bf16, XOR swizzle byte^=((row&7)<<4).
template<int OD, bool DUAL, bool HAS_ADD, bool RELU, bool OUT_F32, bool A0F32>
__global__ __launch_bounds__(256) void k_mm(const void* __restrict__ A0,
                                            const ushort* __restrict__ A1,
                                            const ushort* __restrict__ W0,
                                            const ushort* __restrict__ W1,
                                            const float* __restrict__ bias,
                                            const ushort* __restrict__ add,
                                            void* __restrict__ outp, int N) {
    constexpr int NK    = DUAL ? 4 : 2;
    constexpr int M_REP = (OD == 128) ? 4 : 2;
    constexpr int N_REP = 4;
    constexpr int WROWS = M_REP * 16;

    __shared__ __align__(16) ushort sA[128 * 64];
    __shared__ __align__(16) ushort sW[OD * 64];

    const int t    = threadIdx.x;
    const int wid  = t >> 6;
    const int lane = t & 63;
    const int l15  = lane & 15;
    const int lhi  = lane >> 4;
    const int r0   = blockIdx.x * 128;

    int wm, wn0;
    if (OD == 128) { wm = wid >> 1; wn0 = (wid & 1) * 64; }
    else           { wm = wid;      wn0 = 0; }

    f32x4 zero = {0.f, 0.f, 0.f, 0.f};
    f32x4 acc[M_REP][N_REP];
    #pragma unroll
    for (int m = 0; m < M_REP; ++m)
        #pragma unroll
        for (int n = 0; n < N_REP; ++n) acc[m][n] = zero;

    const ushort* A0b = (const ushort*)A0;
    const float*  A0f = (const float*)A0;

    for (int kc = 0; kc < NK; ++kc) {
        const ushort* Ws = (DUAL && kc >= 2) ? W1 : W0;
        const ushort* As = (DUAL && kc >= 2) ? A1 : A0b;
        const int kloc = (kc & 1) * 64;

        __syncthreads();
        // stage A tile: 128 rows x 64 k
        #pragma unroll
        for (int it = 0; it < 4; ++it) {
            int slot = it * 256 + t;
            int row = slot >> 3, k8 = slot & 7;
            int gr = r0 + row; if (gr >= N) gr = N - 1;
            short8 v;
            if constexpr (A0F32) {
                float4 p = *(const float4*)(A0f + (size_t)gr * 128 + kloc + k8 * 8);
                float4 q = *(const float4*)(A0f + (size_t)gr * 128 + kloc + k8 * 8 + 4);
                v[0] = (short)f2bf(p.x); v[1] = (short)f2bf(p.y);
                v[2] = (short)f2bf(p.z); v[3] = (short)f2bf(p.w);
                v[4] = (short)f2bf(q.x); v[5] = (short)f2bf(q.y);
                v[6] = (short)f2bf(q.z); v[7] = (short)f2bf(q.w);
            } else {
                v = *(const short8*)(As + (size_t)gr * 128 + kloc + k8 * 8);
            }
            *(short8*)((char*)sA + ((row * 128 + k8 * 16) ^ ((row & 7) << 4))) = v;
        }
        // stage W tile: OD rows x 64 k
        #pragma unroll
        for (int it = 0; it < OD / 32; ++it) {
            int slot = it * 256 + t;
            int row = slot >> 3, k8 = slot & 7;
            short8 v = *(const short8*)(Ws + (size_t)row * 128 + kloc + k8 * 8);
            *(short8*)((char*)sW + ((row * 128 + k8 * 16) ^ ((row & 7) << 4))) = v;
        }
        __syncthreads();

        #pragma unroll
        for (int kb = 0; kb < 2; ++kb) {
            short8 af[M_REP], bfr[N_REP];
            #pragma unroll
            for (int m = 0; m < M_REP; ++m) {
                int row = wm * WROWS + m * 16 + l15;
                af[m] = *(const short8*)((const char*)sA +
                        ((row * 128 + kb * 64 + lhi * 16) ^ ((row & 7) << 4)));
            }
            #pragma unroll
            for (int n = 0; n < N_REP; ++n) {
                int colr = wn0 + n * 16 + l15;
                bfr[n] = *(const short8*)((const char*)sW +
                         ((colr * 128 + kb * 64 + lhi * 16) ^ ((colr & 7) << 4)));
            }
            #pragma unroll
            for (int m = 0; m < M_REP; ++m)
                #pragma unroll
                for (int n = 0; n < N_REP; ++n)
                    acc[m][n] = __builtin_amdgcn_mfma_f32_16x16x32_bf16(af[m], bfr[n], acc[m][n], 0, 0, 0);
        }
    }

    float bv[N_REP];
    #pragma unroll
    for (int n = 0; n < N_REP; ++n) bv[n] = bias ? bias[wn0 + n * 16 + l15] : 0.f;

    #pragma unroll
    for (int m = 0; m < M_REP; ++m) {
        #pragma unroll
        for (int r = 0; r < 4; ++r) {
            int grow = r0 + wm * WROWS + m * 16 + lhi * 4 + r;
            if (grow < N) {
                #pragma unroll
                for (int n = 0; n < N_REP; ++n) {
                    int colr = wn0 + n * 16 + l15;
                    float v = acc[m][n][r] + bv[n];
                    if (HAS_ADD) v += bf2f(add[(size_t)grow * OD + colr]);
                    if (RELU) v = fmaxf(v, 0.f);
                    if (OUT_F32) ((float*)outp)[(size_t)grow * OD + colr] = v;
                    else ((ushort*)outp)[(size_t)grow * OD + colr] = f2bf(v);
                }
            }
        }
    }
}

extern "C" void kernel_launch(void* const* d_in, const int* in_sizes, int n_in,
                              void* d_out, int out_size, void* d_ws, size_t ws_size,
                              hipStream_t stream) {
    const float* x     = (const float*)d_in[0];
    const int*   eidx  = (const int*)d_in[1];
    const float* emb_W = (const float*)d_in[2];
    const float* emb_b = (const float*)d_in[3];
    const float* Wl0   = (const float*)d_in[4];
    const float* bl0   = (const float*)d_in[5];
    const float* Wr0   = (const float*)d_in[6];
    const float* Wl1   = (const float*)d_in[7];
    const float* bl1   = (const float*)d_in[8];
    const float* Wr1   = (const float*)d_in[9];
    const float* Wl2   = (const float*)d_in[10];
    const float* bl2   = (const float*)d_in[11];
    const float* Wr2   = (const float*)d_in[12];

    const int N = in_sizes[0] / NODE_D;
    const int E = in_sizes[1] / 2;
    const int* src = eidx;
    const int* dst = eidx + E;
    const int NBK = (N + (1 << BSH) - 1) >> BSH;

    // ---- workspace layout ----
    char* w = (char*)d_ws;
    ushort* h_bf    = (ushort*)w; w += (size_t)N * 128 * sizeof(ushort);
    ushort* mean_bf = (ushort*)w; w += (size_t)N * 128 * sizeof(ushort);
    ushort* wbf     = (ushort*)w; w += (size_t)98304 * sizeof(ushort);
    uint2* ebuf     = (uint2*)w;  w += (size_t)E * sizeof(uint2);
    int* deg    = (int*)w; w += (size_t)N * sizeof(int);
    int* rowptr = (int*)w; w += (size_t)(N + 1) * sizeof(int);
    int* cursor = (int*)w; w += (size_t)N * sizeof(int);
    int* bsums  = (int*)w; w += (size_t)256 * sizeof(int);
    int* bcur   = (int*)w; w += (size_t)NBK * sizeof(int);
    int* col    = (int*)w; w += (size_t)E * sizeof(int);

    const ushort* embB = wbf;
    const ushort* Wl0B = wbf + 16384;
    const ushort* Wr0B = wbf + 32768;
    const ushort* Wl1B = wbf + 49152;
    const ushort* Wr1B = wbf + 65536;
    const ushort* Wl2B = wbf + 81920;
    const ushort* Wr2B = wbf + 90112;

    // layer-2 64-dim buffers alias mean_bf
    ushort* g2 = mean_bf;
    ushort* ga = mean_bf + (size_t)N * 64;

    const int TPB = 256;

    // ---- weight conversion ----
    hipLaunchKernelGGL(k_cvt_w, dim3(384), dim3(TPB), 0, stream,
                       emb_W, Wl0, Wr0, Wl1, Wr1, Wl2, Wr2, wbf);

    // ---- CSR build: hist -> scan -> bucket scatter -> local fill ----
    hipMemsetAsync(deg, 0, (size_t)N * sizeof(int), stream);
    hipLaunchKernelGGL(k_hist, dim3((E + TPB - 1) / TPB), dim3(TPB), 0, stream, dst, deg, E);
    const int NB = (N + SCAN_T * SCAN_I - 1) / (SCAN_T * SCAN_I);
    hipLaunchKernelGGL(k_scan_bsum, dim3(NB), dim3(SCAN_T), 0, stream, deg, bsums, N);
    hipLaunchKernelGGL(k_scan_bsum_excl, dim3(1), dim3(1), 0, stream, bsums, NB, rowptr + N);
    hipLaunchKernelGGL(k_scan_final, dim3(NB), dim3(SCAN_T), 0, stream, deg, bsums, rowptr, cursor, N);
    hipLaunchKernelGGL(k_bcur, dim3((NBK + TPB - 1) / TPB), dim3(TPB), 0, stream, rowptr, bcur, NBK, N);
    hipLaunchKernelGGL(k_scatter, dim3((E + TPB - 1) / TPB), dim3(TPB), 0, stream, src, dst, bcur, ebuf, E);
    hipLaunchKernelGGL(k_fill2, dim3(NBK), dim3(TPB), 0, stream, ebuf, rowptr, cursor, col, N);

    const int dgrid = (N + 127) / 128;
    const int agrid = (N + 3) / 4;

    // ---- embedding: h = x @ emb_W.T + emb_b (f32 A staged with in-reg convert) ----
    hipLaunchKernelGGL((k_mm<128, false, false, false, false, true>), dim3(dgrid), dim3(TPB), 0, stream,
                       (const void*)x, (const ushort*)nullptr, embB, (const ushort*)nullptr,
                       emb_b, (const ushort*)nullptr, h_bf, N);

    // ---- layer 0: h = relu(mean@Wl0.T + bl0 + h@Wr0.T) ----
    hipLaunchKernelGGL((k_aggb<128>), dim3(agrid), dim3(TPB), 0, stream, h_bf, rowptr, col, mean_bf, N);
    hipLaunchKernelGGL((k_mm<128, true, false, true, false, false>), dim3(dgrid), dim3(TPB), 0, stream,
                       (const void*)mean_bf, h_bf, Wl0B, Wr0B, bl0, (const ushort*)nullptr, h_bf, N);

    // ---- layer 1 ----
    hipLaunchKernelGGL((k_aggb<128>), dim3(agrid), dim3(TPB), 0, stream, h_bf, rowptr, col, mean_bf, N);
    hipLaunchKernelGGL((k_mm<128, true, false, true, false, false>), dim3(dgrid), dim3(TPB), 0, stream,
                       (const void*)mean_bf, h_bf, Wl1B, Wr1B, bl1, (const ushort*)nullptr, h_bf, N);

    // ---- layer 2: pre-transform (linearity), aggregate 64-dim, root + add ----
    hipLaunchKernelGGL((k_mm<64, false, false, false, false, false>), dim3(dgrid), dim3(TPB), 0, stream,
                       (const void*)h_bf, (const ushort*)nullptr, Wl2B, (const ushort*)nullptr,
                       (const float*)nullptr, (const ushort*)nullptr, g2, N);
    hipLaunchKernelGGL((k_aggb<64>), dim3(agrid), dim3(TPB), 0, stream, g2, rowptr, col, ga, N);
    hipLaunchKernelGGL((k_mm<64, false, true, false, true, false>), dim3(dgrid), dim3(TPB), 0, stream,
                       (const void*)h_bf, (const ushort*)nullptr, Wr2B, (const ushort*)nullptr,
                       bl2, ga, d_out, N);
}

// Round 5
// 444.648 us; speedup vs baseline: 1.7776x; 1.7776x over previous
//
#include <hip/hip_runtime.h>

typedef __attribute__((ext_vector_type(8))) short short8;
typedef __attribute__((ext_vector_type(4))) float f32x4;

#define NODE_D 128
#define SCAN_T 256
#define SCAN_I 8

__device__ __forceinline__ float bf2f(ushort u) {
    union { uint i; float f; } c; c.i = ((uint)u) << 16; return c.f;
}
__device__ __forceinline__ ushort f2bf(float f) {
    union { float f; uint i; } c; c.f = f;
    return (ushort)((c.i + 0x7FFF + ((c.i >> 16) & 1)) >> 16);
}

// ---------- all 7 weight matrices f32 -> bf16, concatenated dst ----------
__global__ __launch_bounds__(256) void k_cvt_w(const float* __restrict__ s0, const float* __restrict__ s1,
                                               const float* __restrict__ s2, const float* __restrict__ s3,
                                               const float* __restrict__ s4, const float* __restrict__ s5,
                                               const float* __restrict__ s6, ushort* __restrict__ dst) {
    int i = blockIdx.x * 256 + threadIdx.x;
    if (i >= 98304) return;
    const float* s; int off;
    if (i < 16384)      { s = s0; off = i; }
    else if (i < 32768) { s = s1; off = i - 16384; }
    else if (i < 49152) { s = s2; off = i - 32768; }
    else if (i < 65536) { s = s3; off = i - 49152; }
    else if (i < 81920) { s = s4; off = i - 65536; }
    else if (i < 90112) { s = s5; off = i - 81920; }
    else                { s = s6; off = i - 90112; }
    dst[i] = f2bf(s[off]);
}

// ---------- degree histogram ----------
__global__ __launch_bounds__(256) void k_hist(const int* __restrict__ dst,
                                              int* __restrict__ deg, int E) {
    int i = blockIdx.x * 256 + threadIdx.x;
    if (i < E) atomicAdd(&deg[dst[i]], 1);
}

// ---------- scan pass A ----------
__global__ __launch_bounds__(SCAN_T) void k_scan_bsum(const int* __restrict__ deg,
                                                      int* __restrict__ bsums, int n) {
    __shared__ int red[SCAN_T];
    int base = blockIdx.x * SCAN_T * SCAN_I + threadIdx.x * SCAN_I;
    int s = 0;
    #pragma unroll
    for (int i = 0; i < SCAN_I; ++i) {
        int idx = base + i;
        if (idx < n) s += deg[idx];
    }
    red[threadIdx.x] = s;
    __syncthreads();
    for (int st = SCAN_T / 2; st > 0; st >>= 1) {
        if (threadIdx.x < st) red[threadIdx.x] += red[threadIdx.x + st];
        __syncthreads();
    }
    if (threadIdx.x == 0) bsums[blockIdx.x] = red[0];
}

// ---------- scan pass B ----------
__global__ void k_scan_bsum_excl(int* __restrict__ bsums, int nb,
                                 int* __restrict__ rowptr_last) {
    if (blockIdx.x == 0 && threadIdx.x == 0) {
        int run = 0;
        for (int i = 0; i < nb; ++i) {
            int v = bsums[i];
            bsums[i] = run;
            run += v;
        }
        rowptr_last[0] = run;
    }
}

// ---------- scan pass C ----------
__global__ __launch_bounds__(SCAN_T) void k_scan_final(const int* __restrict__ deg,
                                                       const int* __restrict__ bsums,
                                                       int* __restrict__ rowptr,
                                                       int* __restrict__ cursor, int n) {
    __shared__ int ts[SCAN_T];
    int base = blockIdx.x * SCAN_T * SCAN_I + threadIdx.x * SCAN_I;
    int v[SCAN_I];
    int s = 0;
    #pragma unroll
    for (int i = 0; i < SCAN_I; ++i) {
        int idx = base + i;
        v[i] = (idx < n) ? deg[idx] : 0;
        s += v[i];
    }
    ts[threadIdx.x] = s;
    __syncthreads();
    for (int st = 1; st < SCAN_T; st <<= 1) {
        int add = (threadIdx.x >= st) ? ts[threadIdx.x - st] : 0;
        __syncthreads();
        ts[threadIdx.x] += add;
        __syncthreads();
    }
    int excl = (threadIdx.x == 0 ? 0 : ts[threadIdx.x - 1]) + bsums[blockIdx.x];
    #pragma unroll
    for (int i = 0; i < SCAN_I; ++i) {
        int idx = base + i;
        if (idx < n) { rowptr[idx] = excl; cursor[idx] = excl; }
        excl += v[i];
    }
}

// ---------- XCD-partitioned CSR fill ----------
// Block b handles only edges with dst in partition (b&7); under round-robin
// block->XCD dispatch, all writes to a given col/cursor line come from ONE XCD
// -> full-line write-backs, no cross-XCD partial-line duplication. Edge list is
// read 8x but is L2/L3-resident. Atomics stay spread over N cursors (low
// contention; the R4 scatter failure was 781-counter contention, ~180ns/RMW).
__global__ __launch_bounds__(256) void k_fillp(const int* __restrict__ src,
                                               const int* __restrict__ dst,
                                               int* __restrict__ cursor,
                                               int* __restrict__ col,
                                               int E, int psz) {
    int part = blockIdx.x & 7;
    int lo = part * psz, hi = lo + psz;
    int nth = (gridDim.x >> 3) * 256;
    int i = (blockIdx.x >> 3) * 256 + threadIdx.x;
    for (; i < E; i += nth) {
        int d = dst[i];
        if (d >= lo && d < hi) {
            int pos = atomicAdd(&cursor[d], 1);
            col[pos] = src[i];
        }
    }
}

// ---------- mean aggregation over bf16 activations: one wave per node ----------
template<int D>
__global__ __launch_bounds__(256) void k_aggb(const ushort* __restrict__ h,
                                              const int* __restrict__ rowptr,
                                              const int* __restrict__ col,
                                              ushort* __restrict__ mean, int N) {
    int node = blockIdx.x * 4 + (threadIdx.x >> 6);
    if (node >= N) return;
    int lane = threadIdx.x & 63;
    int beg = rowptr[node];
    int end = rowptr[node + 1];
    float inv = 1.f / fmaxf((float)(end - beg), 1.f);
    if constexpr (D == 128) {
        const ushort* base = h + lane * 2;
        float ax = 0.f, ay = 0.f;
        int j = beg;
        for (; j + 7 < end; j += 8) {
            uint v[8];
            #pragma unroll
            for (int q = 0; q < 8; ++q)
                v[q] = *(const uint*)(base + (size_t)col[j + q] * 128);
            #pragma unroll
            for (int q = 0; q < 8; ++q) {
                ax += bf2f((ushort)v[q]);
                ay += bf2f((ushort)(v[q] >> 16));
            }
        }
        for (; j < end; ++j) {
            uint v = *(const uint*)(base + (size_t)col[j] * 128);
            ax += bf2f((ushort)v);
            ay += bf2f((ushort)(v >> 16));
        }
        uint o = (uint)f2bf(ax * inv) | ((uint)f2bf(ay * inv) << 16);
        *(uint*)(mean + (size_t)node * 128 + lane * 2) = o;
    } else {
        const ushort* base = h + lane;
        float ax = 0.f;
        int j = beg;
        for (; j + 7 < end; j += 8) {
            ushort v[8];
            #pragma unroll
            for (int q = 0; q < 8; ++q) v[q] = base[(size_t)col[j + q] * D];
            #pragma unroll
            for (int q = 0; q < 8; ++q) ax += bf2f(v[q]);
        }
        for (; j < end; ++j) ax += bf2f(base[(size_t)col[j] * D]);
        mean[(size_t)node * D + lane] = f2bf(ax * inv);
    }
}

// ---------- MFMA dense: out = A@W0^T (+ A1@W1^T) [+bias] [+add] [+relu] ----------
// A0: [N][128] bf16 (or f32 if A0F32) row-major. W: [OD][128] bf16 row-major.
// Tile: 128 rows x OD cols, 4 waves. LDS [dim][64] bf16, XOR swizzle byte^=((row&7)<<4).
template<int OD, bool DUAL, bool HAS_ADD, bool RELU, bool OUT_F32, bool A0F32>
__global__ __launch_bounds__(256) void k_mm(const void* __restrict__ A0,
                                            const ushort* __restrict__ A1,
                                            const ushort* __restrict__ W0,
                                            const ushort* __restrict__ W1,
                                            const float* __restrict__ bias,
                                            const ushort* __restrict__ add,
                                            void* __restrict__ outp, int N) {
    constexpr int NK    = DUAL ? 4 : 2;
    constexpr int M_REP = (OD == 128) ? 4 : 2;
    constexpr int N_REP = 4;
    constexpr int WROWS = M_REP * 16;

    __shared__ __align__(16) ushort sA[128 * 64];
    __shared__ __align__(16) ushort sW[OD * 64];

    const int t    = threadIdx.x;
    const int wid  = t >> 6;
    const int lane = t & 63;
    const int l15  = lane & 15;
    const int lhi  = lane >> 4;
    const int r0   = blockIdx.x * 128;

    int wm, wn0;
    if (OD == 128) { wm = wid >> 1; wn0 = (wid & 1) * 64; }
    else           { wm = wid;      wn0 = 0; }

    f32x4 zero = {0.f, 0.f, 0.f, 0.f};
    f32x4 acc[M_REP][N_REP];
    #pragma unroll
    for (int m = 0; m < M_REP; ++m)
        #pragma unroll
        for (int n = 0; n < N_REP; ++n) acc[m][n] = zero;

    const ushort* A0b = (const ushort*)A0;
    const float*  A0f = (const float*)A0;

    for (int kc = 0; kc < NK; ++kc) {
        const ushort* Ws = (DUAL && kc >= 2) ? W1 : W0;
        const ushort* As = (DUAL && kc >= 2) ? A1 : A0b;
        const int kloc = (kc & 1) * 64;

        __syncthreads();
        // stage A tile: 128 rows x 64 k
        #pragma unroll
        for (int it = 0; it < 4; ++it) {
            int slot = it * 256 + t;
            int row = slot >> 3, k8 = slot & 7;
            int gr = r0 + row; if (gr >= N) gr = N - 1;
            short8 v;
            if constexpr (A0F32) {
                float4 p = *(const float4*)(A0f + (size_t)gr * 128 + kloc + k8 * 8);
                float4 q = *(const float4*)(A0f + (size_t)gr * 128 + kloc + k8 * 8 + 4);
                v[0] = (short)f2bf(p.x); v[1] = (short)f2bf(p.y);
                v[2] = (short)f2bf(p.z); v[3] = (short)f2bf(p.w);
                v[4] = (short)f2bf(q.x); v[5] = (short)f2bf(q.y);
                v[6] = (short)f2bf(q.z); v[7] = (short)f2bf(q.w);
            } else {
                v = *(const short8*)(As + (size_t)gr * 128 + kloc + k8 * 8);
            }
            *(short8*)((char*)sA + ((row * 128 + k8 * 16) ^ ((row & 7) << 4))) = v;
        }
        // stage W tile: OD rows x 64 k
        #pragma unroll
        for (int it = 0; it < OD / 32; ++it) {
            int slot = it * 256 + t;
            int row = slot >> 3, k8 = slot & 7;
            short8 v = *(const short8*)(Ws + (size_t)row * 128 + kloc + k8 * 8);
            *(short8*)((char*)sW + ((row * 128 + k8 * 16) ^ ((row & 7) << 4))) = v;
        }
        __syncthreads();

        #pragma unroll
        for (int kb = 0; kb < 2; ++kb) {
            short8 af[M_REP], bfr[N_REP];
            #pragma unroll
            for (int m = 0; m < M_REP; ++m) {
                int row = wm * WROWS + m * 16 + l15;
                af[m] = *(const short8*)((const char*)sA +
                        ((row * 128 + kb * 64 + lhi * 16) ^ ((row & 7) << 4)));
            }
            #pragma unroll
            for (int n = 0; n < N_REP; ++n) {
                int colr = wn0 + n * 16 + l15;
                bfr[n] = *(const short8*)((const char*)sW +
                         ((colr * 128 + kb * 64 + lhi * 16) ^ ((colr & 7) << 4)));
            }
            #pragma unroll
            for (int m = 0; m < M_REP; ++m)
                #pragma unroll
                for (int n = 0; n < N_REP; ++n)
                    acc[m][n] = __builtin_amdgcn_mfma_f32_16x16x32_bf16(af[m], bfr[n], acc[m][n], 0, 0, 0);
        }
    }

    float bv[N_REP];
    #pragma unroll
    for (int n = 0; n < N_REP; ++n) bv[n] = bias ? bias[wn0 + n * 16 + l15] : 0.f;

    #pragma unroll
    for (int m = 0; m < M_REP; ++m) {
        #pragma unroll
        for (int r = 0; r < 4; ++r) {
            int grow = r0 + wm * WROWS + m * 16 + lhi * 4 + r;
            if (grow < N) {
                #pragma unroll
                for (int n = 0; n < N_REP; ++n) {
                    int colr = wn0 + n * 16 + l15;
                    float v = acc[m][n][r] + bv[n];
                    if (HAS_ADD) v += bf2f(add[(size_t)grow * OD + colr]);
                    if (RELU) v = fmaxf(v, 0.f);
                    if (OUT_F32) ((float*)outp)[(size_t)grow * OD + colr] = v;
                    else ((ushort*)outp)[(size_t)grow * OD + colr] = f2bf(v);
                }
            }
        }
    }
}

extern "C" void kernel_launch(void* const* d_in, const int* in_sizes, int n_in,
                              void* d_out, int out_size, void* d_ws, size_t ws_size,
                              hipStream_t stream) {
    const float* x     = (const float*)d_in[0];
    const int*   eidx  = (const int*)d_in[1];
    const float* emb_W = (const float*)d_in[2];
    const float* emb_b = (const float*)d_in[3];
    const float* Wl0   = (const float*)d_in[4];
    const float* bl0   = (const float*)d_in[5];
    const float* Wr0   = (const float*)d_in[6];
    const float* Wl1   = (const float*)d_in[7];
    const float* bl1   = (const float*)d_in[8];
    const float* Wr1   = (const float*)d_in[9];
    const float* Wl2   = (const float*)d_in[10];
    const float* bl2   = (const float*)d_in[11];
    const float* Wr2   = (const float*)d_in[12];

    const int N = in_sizes[0] / NODE_D;
    const int E = in_sizes[1] / 2;
    const int* src = eidx;
    const int* dst = eidx + E;

    // ---- workspace layout ----
    char* w = (char*)d_ws;
    ushort* h_bf    = (ushort*)w; w += (size_t)N * 128 * sizeof(ushort);
    ushort* mean_bf = (ushort*)w; w += (size_t)N * 128 * sizeof(ushort);
    ushort* wbf     = (ushort*)w; w += (size_t)98304 * sizeof(ushort);
    int* deg    = (int*)w; w += (size_t)N * sizeof(int);
    int* rowptr = (int*)w; w += (size_t)(N + 1) * sizeof(int);
    int* cursor = (int*)w; w += (size_t)N * sizeof(int);
    int* bsums  = (int*)w; w += (size_t)256 * sizeof(int);
    int* col    = (int*)w; w += (size_t)E * sizeof(int);

    const ushort* embB = wbf;
    const ushort* Wl0B = wbf + 16384;
    const ushort* Wr0B = wbf + 32768;
    const ushort* Wl1B = wbf + 49152;
    const ushort* Wr1B = wbf + 65536;
    const ushort* Wl2B = wbf + 81920;
    const ushort* Wr2B = wbf + 90112;

    // layer-2 64-dim buffers alias mean_bf
    ushort* g2 = mean_bf;
    ushort* ga = mean_bf + (size_t)N * 64;

    const int TPB = 256;

    // ---- weight conversion ----
    hipLaunchKernelGGL(k_cvt_w, dim3(384), dim3(TPB), 0, stream,
                       emb_W, Wl0, Wr0, Wl1, Wr1, Wl2, Wr2, wbf);

    // ---- CSR build: hist -> scan -> XCD-partitioned fill ----
    hipMemsetAsync(deg, 0, (size_t)N * sizeof(int), stream);
    hipLaunchKernelGGL(k_hist, dim3((E + TPB - 1) / TPB), dim3(TPB), 0, stream, dst, deg, E);
    const int NB = (N + SCAN_T * SCAN_I - 1) / (SCAN_T * SCAN_I);
    hipLaunchKernelGGL(k_scan_bsum, dim3(NB), dim3(SCAN_T), 0, stream, deg, bsums, N);
    hipLaunchKernelGGL(k_scan_bsum_excl, dim3(1), dim3(1), 0, stream, bsums, NB, rowptr + N);
    hipLaunchKernelGGL(k_scan_final, dim3(NB), dim3(SCAN_T), 0, stream, deg, bsums, rowptr, cursor, N);
    const int psz = (N + 7) / 8;
    hipLaunchKernelGGL(k_fillp, dim3(2048), dim3(TPB), 0, stream, src, dst, cursor, col, E, psz);

    const int dgrid = (N + 127) / 128;
    const int agrid = (N + 3) / 4;

    // ---- embedding: h = x @ emb_W.T + emb_b (f32 A staged with in-reg convert) ----
    hipLaunchKernelGGL((k_mm<128, false, false, false, false, true>), dim3(dgrid), dim3(TPB), 0, stream,
                       (const void*)x, (const ushort*)nullptr, embB, (const ushort*)nullptr,
                       emb_b, (const ushort*)nullptr, h_bf, N);

    // ---- layer 0: h = relu(mean@Wl0.T + bl0 + h@Wr0.T) ----
    hipLaunchKernelGGL((k_aggb<128>), dim3(agrid), dim3(TPB), 0, stream, h_bf, rowptr, col, mean_bf, N);
    hipLaunchKernelGGL((k_mm<128, true, false, true, false, false>), dim3(dgrid), dim3(TPB), 0, stream,
                       (const void*)mean_bf, h_bf, Wl0B, Wr0B, bl0, (const ushort*)nullptr, h_bf, N);

    // ---- layer 1 ----
    hipLaunchKernelGGL((k_aggb<128>), dim3(agrid), dim3(TPB), 0, stream, h_bf, rowptr, col, mean_bf, N);
    hipLaunchKernelGGL((k_mm<128, true, false, true, false, false>), dim3(dgrid), dim3(TPB), 0, stream,
                       (const void*)mean_bf, h_bf, Wl1B, Wr1B, bl1, (const ushort*)nullptr, h_bf, N);

    // ---- layer 2: pre-transform (linearity), aggregate 64-dim, root + add ----
    hipLaunchKernelGGL((k_mm<64, false, false, false, false, false>), dim3(dgrid), dim3(TPB), 0, stream,
                       (const void*)h_bf, (const ushort*)nullptr, Wl2B, (const ushort*)nullptr,
                       (const float*)nullptr, (const ushort*)nullptr, g2, N);
    hipLaunchKernelGGL((k_aggb<64>), dim3(agrid), dim3(TPB), 0, stream, g2, rowptr, col, ga, N);
    hipLaunchKernelGGL((k_mm<64, false, true, false, true, false>), dim3(dgrid), dim3(TPB), 0, stream,
                       (const void*)h_bf, (const ushort*)nullptr, Wr2B, (const ushort*)nullptr,
                       bl2, ga, d_out, N);
}